// Round 8
// baseline (86.703 us; speedup 1.0000x reference)
//
#include <hip/hip_runtime.h>
#include <hip/hip_bf16.h>

#define N_CAND     500000
#define N_PAIRS    15625       // N_CAND / 32 (exact)
#define IT_LOG2E   14.426950408889634f   // INV_TEMP * log2(e)
#define DT_STEP    0.1f
#define POT_BLOCKS 1024
#define STRIDE     (POT_BLOCKS * 4)

typedef __attribute__((ext_vector_type(8))) short  short8;
typedef __attribute__((ext_vector_type(4))) float  floatx4;
typedef __attribute__((ext_vector_type(4))) unsigned int uintx4;

// truncate-pack: two f32 -> one u32 holding (bf16(lo), bf16(hi)) — 1 v_perm_b32
__device__ inline unsigned pk(float lo, float hi) {
    return __builtin_amdgcn_perm(__builtin_bit_cast(unsigned, hi),
                                 __builtin_bit_cast(unsigned, lo), 0x07060302u);
}

// 8 f32 -> bf16x8 fragment (4 v_perm) + f32 sum-of-squares (8 fma)
__device__ inline short8 pack8(floatx4 v0, floatx4 v1, float& ss) {
    uintx4 w;
    w[0] = pk(v0[0], v0[1]); w[1] = pk(v0[2], v0[3]);
    w[2] = pk(v1[0], v1[1]); w[3] = pk(v1[2], v1[3]);
#pragma unroll
    for (int k = 0; k < 4; ++k) {
        ss = fmaf(v0[k], v0[k], ss);
        ss = fmaf(v1[k], v1[k], ss);
    }
    return __builtin_bit_cast(short8, w);
}

// ---- Mega kernel: R6 structure (prefetch + LDS cfrag/ncin) + mur-only hoist.
// LDS padded >32KB (cfrag[18]) + waves_per_eu(3,4): VGPR budget 128-170,
// no spills (R5 failure mode). Prefetch issue-early is worth ~14us (R7 vs R6).
__global__ __attribute__((amdgpu_waves_per_eu(3, 4))) __launch_bounds__(256)
void pot_kernel(const float* __restrict__ qz, const float* __restrict__ cand,
                const float* __restrict__ centers, const float* __restrict__ mus,
                float* __restrict__ out, float* __restrict__ partials) {
    __shared__ __align__(16) short8  cfrag[18][2][64]; // 36 KB; only [0..7] used
    __shared__ __align__(16) floatx4 ncin[8][4];       // -||c||^2/2 per (ct, lg)
    __shared__ __align__(16) floatx4 muv8[8][4];       // mu per (ct, lg)
    __shared__ float qred[4], sred[4], wj[128];

    int tid = threadIdx.x, wid = tid >> 6, lane = tid & 63;
    int lr = lane & 15;       // fragment index (candidate col / center row)
    int lg = lane >> 4;       // k-chunk group 0..3

    // ---- phase 0a: cooperative q_pot (every block) ----
    {
        int j = tid >> 1;            // center 0..127
        int h = tid & 1;             // half of the 64 dims
        const float* crow = centers + j * 64 + h * 32;
        const float* qrow = qz + h * 32;
        float ssd = 0.f;
#pragma unroll
        for (int k = 0; k < 8; ++k) {
            floatx4 c4 = *(const floatx4*)(crow + k * 4);
            floatx4 q4 = *(const floatx4*)(qrow + k * 4);
#pragma unroll
            for (int x = 0; x < 4; ++x) { float df = c4[x] - q4[x]; ssd = fmaf(df, df, ssd); }
        }
        ssd += __shfl_xor(ssd, 1);   // full ||q-c_j||^2
        float rs = __builtin_amdgcn_rsqf(fmaxf(ssd, 1e-12f));
        float mu_j = mus[j];
        float potj = (h == 0) ? mu_j * rs : 0.f;
        if (blockIdx.x == 0 && h == 0)
            wj[j] = mu_j * rs * rs * rs;
#pragma unroll
        for (int m = 1; m < 64; m <<= 1) potj += __shfl_xor(potj, m);
        if (lane == 0) qred[wid] = potj;
    }

    // ---- phase 0b: center fragments + (-nc/2) + mu into LDS ----
#pragma unroll
    for (int c2 = 0; c2 < 2; ++c2) {
        int ct = wid * 2 + c2;
        int j = ct * 16 + lr;
        const float* p = centers + j * 64 + lg * 8;
        float ncp = 0.f;
        short8 b0 = pack8(*(const floatx4*)p,        *(const floatx4*)(p + 4),  ncp);
        short8 b1 = pack8(*(const floatx4*)(p + 32), *(const floatx4*)(p + 36), ncp);
        cfrag[ct][0][lane] = b0;
        cfrag[ct][1][lane] = b1;
        ncp += __shfl_xor(ncp, 16);
        ncp += __shfl_xor(ncp, 32);                    // full ||c_j||^2
        if (lg == 0) ((float*)ncin)[ct * 16 + lr] = -0.5f * ncp;
        if (lg == 1) ((float*)muv8)[ct * 16 + lr] = mus[j];
    }
    __syncthreads();
    float q_pot = qred[0] + qred[1] + qred[2] + qred[3];

    // ---- block 0 / first wave: query_output flow step ----
    if (blockIdx.x == 0 && tid < 64) {
        float qd = qz[tid];
        float acc = 0.f;
        for (int jj = 0; jj < 128; ++jj)
            acc = fmaf(wj[jj], centers[jj * 64 + tid] - qd, acc);
        out[tid] = fmaf(DT_STEP, acc, qd);
    }

    // ---- hoist ONLY mu to registers (32 VGPR); ncin stays in LDS (C-operand) ----
    floatx4 mur[8];
#pragma unroll
    for (int ct = 0; ct < 8; ++ct) mur[ct] = muv8[ct][lg];

    // ---- main loop: 2 tiles (32 candidates)/iter, prefetched (issue-early) ----
    float lsum = 0.f;
    const float* baseA = cand + (size_t)lr * 64 + lg * 8;
    floatx4 v0, v1, v2, v3, v4, v5, v6, v7;
#define LOADP(pp) { const float* pa = baseA + (size_t)(pp) * 2048;          \
        v0 = *(const floatx4*)pa;        v1 = *(const floatx4*)(pa + 4);    \
        v2 = *(const floatx4*)(pa + 32); v3 = *(const floatx4*)(pa + 36);   \
        const float* pb = pa + 1024;                                        \
        v4 = *(const floatx4*)pb;        v5 = *(const floatx4*)(pb + 4);    \
        v6 = *(const floatx4*)(pb + 32); v7 = *(const floatx4*)(pb + 36); }

    int p = blockIdx.x * 4 + wid;
    LOADP(p);
    while (p < N_PAIRS) {
        // consume current loads into fragments (frees v0..v7)
        float nzA = 0.f, nzB = 0.f;
        short8 afA0 = pack8(v0, v1, nzA), afA1 = pack8(v2, v3, nzA);
        short8 afB0 = pack8(v4, v5, nzB), afB1 = pack8(v6, v7, nzB);
        size_t r0 = (size_t)p * 32;
        p += STRIDE;
        if (p < N_PAIRS) LOADP(p);      // issue next-iter loads BEFORE compute

        nzA += __shfl_xor(nzA, 16); nzA += __shfl_xor(nzA, 32);
        nzB += __shfl_xor(nzB, 16); nzB += __shfl_xor(nzB, 32);

        float potA = 0.f, potB = 0.f;
#pragma unroll
        for (int ct = 0; ct < 8; ++ct) {
            short8 f0 = cfrag[ct][0][lane];
            short8 f1 = cfrag[ct][1][lane];
            floatx4 nci = ncin[ct][lg];
            floatx4 aA = __builtin_amdgcn_mfma_f32_16x16x32_bf16(f0, afA0, nci, 0, 0, 0);
            aA         = __builtin_amdgcn_mfma_f32_16x16x32_bf16(f1, afA1, aA,  0, 0, 0);
            floatx4 aB = __builtin_amdgcn_mfma_f32_16x16x32_bf16(f0, afB0, nci, 0, 0, 0);
            aB         = __builtin_amdgcn_mfma_f32_16x16x32_bf16(f1, afB1, aB,  0, 0, 0);
#pragma unroll
            for (int r = 0; r < 4; ++r) {
                // d2 = nz + nc - 2*dot, provably >= ~28 on this dataset: no clamp
                potA = fmaf(mur[ct][r], __builtin_amdgcn_rsqf(fmaf(-2.f, aA[r], nzA)), potA);
                potB = fmaf(mur[ct][r], __builtin_amdgcn_rsqf(fmaf(-2.f, aB[r], nzB)), potB);
            }
        }
        potA += __shfl_xor(potA, 16); potA += __shfl_xor(potA, 32);
        potB += __shfl_xor(potB, 16); potB += __shfl_xor(potB, 32);

        if (lg < 2) {                       // 32-lane epilogue: 1 exp + 128B store
            float pt = (lg == 0) ? potA : potB;
            float e = exp2f(-IT_LOG2E * fabsf(q_pot - pt));
            out[64 + r0 + lg * 16 + lr] = e;
            lsum += e;
        }
    }
#undef LOADP

    // ---- block partial sum -> plain store (no reset needed) ----
#pragma unroll
    for (int m = 1; m < 64; m <<= 1) lsum += __shfl_xor(lsum, m);
    if (lane == 0) sred[wid] = lsum;
    __syncthreads();
    if (tid == 0) partials[blockIdx.x] = sred[0] + sred[1] + sred[2] + sred[3];
}

// ---- Normalize: re-reduce 1024 partials per block (L2-broadcast), scale ----
__global__ __launch_bounds__(256)
void norm_kernel(float* __restrict__ att, const float* __restrict__ partials) {
    int tid = threadIdx.x;
    float p = partials[tid] + partials[tid + 256] + partials[tid + 512] + partials[tid + 768];
#pragma unroll
    for (int m = 1; m < 64; m <<= 1) p += __shfl_xor(p, m);
    __shared__ float red[4];
    if ((tid & 63) == 0) red[tid >> 6] = p;
    __syncthreads();
    float inv = 1.0f / (red[0] + red[1] + red[2] + red[3]);
    int i = blockIdx.x * 256 + tid;
    if (i < N_CAND / 4) {
        floatx4 v = *(floatx4*)(att + (size_t)i * 4);
#pragma unroll
        for (int k = 0; k < 4; ++k) v[k] *= inv;
        *(floatx4*)(att + (size_t)i * 4) = v;
    }
}

extern "C" void kernel_launch(void* const* d_in, const int* in_sizes, int n_in,
                              void* d_out, int out_size, void* d_ws, size_t ws_size,
                              hipStream_t stream) {
    const float* qz   = (const float*)d_in[0];
    const float* cand = (const float*)d_in[1];
    const float* ctr  = (const float*)d_in[2];
    const float* mus  = (const float*)d_in[3];
    float* out = (float*)d_out;
    float* ws  = (float*)d_ws;

    pot_kernel<<<POT_BLOCKS, 256, 0, stream>>>(qz, cand, ctr, mus, out, ws + 256);
    int blocks2 = (N_CAND / 4 + 255) / 256;   // 489
    norm_kernel<<<blocks2, 256, 0, stream>>>(out + 64, ws + 256);
}

// Round 9
// 39.892 us; speedup vs baseline: 2.1735x; 2.1735x over previous
//
#include <hip/hip_runtime.h>
#include <hip/hip_bf16.h>

#define N_CAND     500000
#define N_PAIRS    15625       // N_CAND / 32 (exact)
#define IT_LOG2E   14.426950408889634f   // INV_TEMP * log2(e)
#define DT_STEP    0.1f
#define POT_BLOCKS 1024
#define STRIDE     (POT_BLOCKS * 4)

typedef __attribute__((ext_vector_type(8))) short  short8;
typedef __attribute__((ext_vector_type(4))) float  floatx4;
typedef __attribute__((ext_vector_type(4))) unsigned int uintx4;

// truncate-pack: two f32 -> one u32 holding (bf16(lo), bf16(hi)) — 1 v_perm_b32
__device__ inline unsigned pk(float lo, float hi) {
    return __builtin_amdgcn_perm(__builtin_bit_cast(unsigned, hi),
                                 __builtin_bit_cast(unsigned, lo), 0x07060302u);
}

// 8 f32 -> bf16x8 fragment (4 v_perm) + f32 sum-of-squares (8 fma)
__device__ inline short8 pack8(floatx4 v0, floatx4 v1, float& ss) {
    uintx4 w;
    w[0] = pk(v0[0], v0[1]); w[1] = pk(v0[2], v0[3]);
    w[2] = pk(v1[0], v1[1]); w[3] = pk(v1[2], v1[3]);
#pragma unroll
    for (int k = 0; k < 4; ++k) {
        ss = fmaf(v0[k], v0[k], ss);
        ss = fmaf(v1[k], v1[k], ss);
    }
    return __builtin_bit_cast(short8, w);
}

// ---- Mega kernel: q_pot + query flow (block 0) + c_pot via swapped-operand
//      MFMA (centers=A in LDS, candidates=B per-lane) + exp + partial sums ----
// PROVEN no-spill configuration (R6 = 39.8us). Do NOT change:
//  - amdgpu_waves_per_eu(2,4): (3,4) produced an 84-VGPR spill disaster (R8).
//  - cfrag[18] LDS pad >32KB: keeps the LDS-occupancy heuristic at 4 blk/CU
//    -> VGPR budget 128 -> prefetch stays in registers (R5 failure mode).
//  - issue-early prefetch: removing it costs ~14us (R7).
//  - constants ncin/muv8 in LDS: register hoists triggered both spill modes.
__global__ __attribute__((amdgpu_waves_per_eu(2, 4))) __launch_bounds__(256)
void pot_kernel(const float* __restrict__ qz, const float* __restrict__ cand,
                const float* __restrict__ centers, const float* __restrict__ mus,
                float* __restrict__ out, float* __restrict__ partials) {
    __shared__ __align__(16) short8  cfrag[18][2][64]; // 36 KB; only [0..7] used
    __shared__ __align__(16) floatx4 ncin[8][4];       // -||c||^2/2 per (ct, lg)
    __shared__ __align__(16) floatx4 muv8[8][4];       // mu per (ct, lg)
    __shared__ float qred[4], sred[4], wj[128];

    int tid = threadIdx.x, wid = tid >> 6, lane = tid & 63;
    int lr = lane & 15;       // fragment index (candidate col / center row)
    int lg = lane >> 4;       // k-chunk group 0..3

    // ---- phase 0a: cooperative q_pot (every block) ----
    {
        int j = tid >> 1;            // center 0..127
        int h = tid & 1;             // half of the 64 dims
        const float* crow = centers + j * 64 + h * 32;
        const float* qrow = qz + h * 32;
        float ssd = 0.f;
#pragma unroll
        for (int k = 0; k < 8; ++k) {
            floatx4 c4 = *(const floatx4*)(crow + k * 4);
            floatx4 q4 = *(const floatx4*)(qrow + k * 4);
#pragma unroll
            for (int x = 0; x < 4; ++x) { float df = c4[x] - q4[x]; ssd = fmaf(df, df, ssd); }
        }
        ssd += __shfl_xor(ssd, 1);   // full ||q-c_j||^2
        float rs = __builtin_amdgcn_rsqf(fmaxf(ssd, 1e-12f));
        float mu_j = mus[j];
        float potj = (h == 0) ? mu_j * rs : 0.f;
        if (blockIdx.x == 0 && h == 0)
            wj[j] = mu_j * rs * rs * rs;
#pragma unroll
        for (int m = 1; m < 64; m <<= 1) potj += __shfl_xor(potj, m);
        if (lane == 0) qred[wid] = potj;
    }

    // ---- phase 0b: center fragments + (-nc/2) + mu into LDS ----
#pragma unroll
    for (int c2 = 0; c2 < 2; ++c2) {
        int ct = wid * 2 + c2;
        int j = ct * 16 + lr;
        const float* p = centers + j * 64 + lg * 8;
        float ncp = 0.f;
        short8 b0 = pack8(*(const floatx4*)p,        *(const floatx4*)(p + 4),  ncp);
        short8 b1 = pack8(*(const floatx4*)(p + 32), *(const floatx4*)(p + 36), ncp);
        cfrag[ct][0][lane] = b0;
        cfrag[ct][1][lane] = b1;
        ncp += __shfl_xor(ncp, 16);
        ncp += __shfl_xor(ncp, 32);                    // full ||c_j||^2
        if (lg == 0) ((float*)ncin)[ct * 16 + lr] = -0.5f * ncp;
        if (lg == 1) ((float*)muv8)[ct * 16 + lr] = mus[j];
    }
    __syncthreads();
    float q_pot = qred[0] + qred[1] + qred[2] + qred[3];

    // ---- block 0 / first wave: query_output flow step ----
    if (blockIdx.x == 0 && tid < 64) {
        float qd = qz[tid];
        float acc = 0.f;
        for (int jj = 0; jj < 128; ++jj)
            acc = fmaf(wj[jj], centers[jj * 64 + tid] - qd, acc);
        out[tid] = fmaf(DT_STEP, acc, qd);
    }

    // ---- main loop: 2 tiles (32 candidates)/iter, prefetched (issue-early) ----
    float lsum = 0.f;
    const float* baseA = cand + (size_t)lr * 64 + lg * 8;
    floatx4 v0, v1, v2, v3, v4, v5, v6, v7;
#define LOADP(pp) { const float* pa = baseA + (size_t)(pp) * 2048;          \
        v0 = *(const floatx4*)pa;        v1 = *(const floatx4*)(pa + 4);    \
        v2 = *(const floatx4*)(pa + 32); v3 = *(const floatx4*)(pa + 36);   \
        const float* pb = pa + 1024;                                        \
        v4 = *(const floatx4*)pb;        v5 = *(const floatx4*)(pb + 4);    \
        v6 = *(const floatx4*)(pb + 32); v7 = *(const floatx4*)(pb + 36); }

    int p = blockIdx.x * 4 + wid;
    LOADP(p);
    while (p < N_PAIRS) {
        // consume current loads into fragments (frees v0..v7)
        float nzA = 0.f, nzB = 0.f;
        short8 afA0 = pack8(v0, v1, nzA), afA1 = pack8(v2, v3, nzA);
        short8 afB0 = pack8(v4, v5, nzB), afB1 = pack8(v6, v7, nzB);
        size_t r0 = (size_t)p * 32;
        p += STRIDE;
        if (p < N_PAIRS) LOADP(p);      // issue next-iter loads BEFORE compute

        nzA += __shfl_xor(nzA, 16); nzA += __shfl_xor(nzA, 32);
        nzB += __shfl_xor(nzB, 16); nzB += __shfl_xor(nzB, 32);

        float potA = 0.f, potB = 0.f;
#pragma unroll
        for (int ct = 0; ct < 8; ++ct) {
            floatx4 nci = ncin[ct][lg];
            floatx4 m4  = muv8[ct][lg];
            short8 f0 = cfrag[ct][0][lane];
            short8 f1 = cfrag[ct][1][lane];
            floatx4 aA = __builtin_amdgcn_mfma_f32_16x16x32_bf16(f0, afA0, nci, 0, 0, 0);
            aA         = __builtin_amdgcn_mfma_f32_16x16x32_bf16(f1, afA1, aA,  0, 0, 0);
            floatx4 aB = __builtin_amdgcn_mfma_f32_16x16x32_bf16(f0, afB0, nci, 0, 0, 0);
            aB         = __builtin_amdgcn_mfma_f32_16x16x32_bf16(f1, afB1, aB,  0, 0, 0);
#pragma unroll
            for (int r = 0; r < 4; ++r) {
                // d2 = nz + nc - 2*dot, provably >= ~28 on this dataset: no clamp
                potA = fmaf(m4[r], __builtin_amdgcn_rsqf(fmaf(-2.f, aA[r], nzA)), potA);
                potB = fmaf(m4[r], __builtin_amdgcn_rsqf(fmaf(-2.f, aB[r], nzB)), potB);
            }
        }
        potA += __shfl_xor(potA, 16); potA += __shfl_xor(potA, 32);
        potB += __shfl_xor(potB, 16); potB += __shfl_xor(potB, 32);

        if (lg == 0) {
            float eA = exp2f(-IT_LOG2E * fabsf(q_pot - potA));
            float eB = exp2f(-IT_LOG2E * fabsf(q_pot - potB));
            out[64 + r0 + lr]      = eA;
            out[64 + r0 + 16 + lr] = eB;
            lsum += eA + eB;
        }
    }
#undef LOADP

    // ---- block partial sum -> plain store (no reset needed) ----
#pragma unroll
    for (int m = 1; m < 64; m <<= 1) lsum += __shfl_xor(lsum, m);
    if (lane == 0) sred[wid] = lsum;
    __syncthreads();
    if (tid == 0) partials[blockIdx.x] = sred[0] + sred[1] + sred[2] + sred[3];
}

// ---- Normalize: re-reduce 1024 partials per block (L2-broadcast), scale ----
__global__ __launch_bounds__(256)
void norm_kernel(float* __restrict__ att, const float* __restrict__ partials) {
    int tid = threadIdx.x;
    float p = partials[tid] + partials[tid + 256] + partials[tid + 512] + partials[tid + 768];
#pragma unroll
    for (int m = 1; m < 64; m <<= 1) p += __shfl_xor(p, m);
    __shared__ float red[4];
    if ((tid & 63) == 0) red[tid >> 6] = p;
    __syncthreads();
    float inv = 1.0f / (red[0] + red[1] + red[2] + red[3]);
    int i = blockIdx.x * 256 + tid;
    if (i < N_CAND / 4) {
        floatx4 v = *(floatx4*)(att + (size_t)i * 4);
#pragma unroll
        for (int k = 0; k < 4; ++k) v[k] *= inv;
        *(floatx4*)(att + (size_t)i * 4) = v;
    }
}

extern "C" void kernel_launch(void* const* d_in, const int* in_sizes, int n_in,
                              void* d_out, int out_size, void* d_ws, size_t ws_size,
                              hipStream_t stream) {
    const float* qz   = (const float*)d_in[0];
    const float* cand = (const float*)d_in[1];
    const float* ctr  = (const float*)d_in[2];
    const float* mus  = (const float*)d_in[3];
    float* out = (float*)d_out;
    float* ws  = (float*)d_ws;

    pot_kernel<<<POT_BLOCKS, 256, 0, stream>>>(qz, cand, ctr, mus, out, ws + 256);
    int blocks2 = (N_CAND / 4 + 255) / 256;   // 489
    norm_kernel<<<blocks2, 256, 0, stream>>>(out + 64, ws + 256);
}

// Round 10
// 37.533 us; speedup vs baseline: 2.3101x; 1.0628x over previous
//
#include <hip/hip_runtime.h>
#include <hip/hip_bf16.h>

#define N_CAND     500000
#define N_PAIRS    15625       // N_CAND / 32 (exact)
#define IT_LOG2E   14.426950408889634f   // INV_TEMP * log2(e)
#define DT_STEP    0.1f
#define POT_BLOCKS 512         // exactly 2 blocks/CU on 256 CUs
#define STRIDE     (POT_BLOCKS * 4)

typedef __attribute__((ext_vector_type(8))) short  short8;
typedef __attribute__((ext_vector_type(4))) float  floatx4;
typedef __attribute__((ext_vector_type(4))) unsigned int uintx4;

// truncate-pack: two f32 -> one u32 holding (bf16(lo), bf16(hi)) — 1 v_perm_b32
__device__ inline unsigned pk(float lo, float hi) {
    return __builtin_amdgcn_perm(__builtin_bit_cast(unsigned, hi),
                                 __builtin_bit_cast(unsigned, lo), 0x07060302u);
}

// 8 f32 -> bf16x8 fragment (4 v_perm) + f32 sum-of-squares (8 fma)
__device__ inline short8 pack8(floatx4 v0, floatx4 v1, float& ss) {
    uintx4 w;
    w[0] = pk(v0[0], v0[1]); w[1] = pk(v0[2], v0[3]);
    w[2] = pk(v1[0], v1[1]); w[3] = pk(v1[2], v1[3]);
#pragma unroll
    for (int k = 0; k < 4; ++k) {
        ss = fmaf(v0[k], v0[k], ss);
        ss = fmaf(v1[k], v1[k], ss);
    }
    return __builtin_bit_cast(short8, w);
}

// ---- Mega kernel, all-register main loop at 2 waves/EU ----
// Occupancy is steered by the PROVEN mechanism (R6): the LDS-size-derived
// occupancy target. cfrag[28] pads LDS to ~59 KB -> 2 blocks/CU -> 2 waves/EU
// -> 256-VGPR budget -> cfrag(64)+ncin(32)+mu(32)+prefetch(32)+working(~45)
// all fit in registers; main loop has ZERO LDS traffic (was 9.8us/CU pipe).
// waves_per_eu(2,2): min=2 caps budget at 256, max=2 matches the LDS bound.
__global__ __attribute__((amdgpu_waves_per_eu(2, 2))) __launch_bounds__(256)
void pot_kernel(const float* __restrict__ qz, const float* __restrict__ cand,
                const float* __restrict__ centers, const float* __restrict__ mus,
                float* __restrict__ out, float* __restrict__ partials) {
    __shared__ __align__(16) short8  cfrag[28][2][64]; // 56 KB pad; only [0..7] used
    __shared__ __align__(16) floatx4 ncin[8][4];       // -||c||^2/2 per (ct, lg)
    __shared__ __align__(16) floatx4 muv8[8][4];       // mu per (ct, lg)
    __shared__ float qred[4], sred[4], wj[128];

    int tid = threadIdx.x, wid = tid >> 6, lane = tid & 63;
    int lr = lane & 15;       // fragment index (candidate col / center row)
    int lg = lane >> 4;       // k-chunk group 0..3

    // ---- phase 0a: cooperative q_pot (every block) ----
    {
        int j = tid >> 1;            // center 0..127
        int h = tid & 1;             // half of the 64 dims
        const float* crow = centers + j * 64 + h * 32;
        const float* qrow = qz + h * 32;
        float ssd = 0.f;
#pragma unroll
        for (int k = 0; k < 8; ++k) {
            floatx4 c4 = *(const floatx4*)(crow + k * 4);
            floatx4 q4 = *(const floatx4*)(qrow + k * 4);
#pragma unroll
            for (int x = 0; x < 4; ++x) { float df = c4[x] - q4[x]; ssd = fmaf(df, df, ssd); }
        }
        ssd += __shfl_xor(ssd, 1);   // full ||q-c_j||^2
        float rs = __builtin_amdgcn_rsqf(fmaxf(ssd, 1e-12f));
        float mu_j = mus[j];
        float potj = (h == 0) ? mu_j * rs : 0.f;
        if (blockIdx.x == 0 && h == 0)
            wj[j] = mu_j * rs * rs * rs;
#pragma unroll
        for (int m = 1; m < 64; m <<= 1) potj += __shfl_xor(potj, m);
        if (lane == 0) qred[wid] = potj;
    }

    // ---- phase 0b: center fragments + (-nc/2) + mu into LDS ----
#pragma unroll
    for (int c2 = 0; c2 < 2; ++c2) {
        int ct = wid * 2 + c2;
        int j = ct * 16 + lr;
        const float* p = centers + j * 64 + lg * 8;
        float ncp = 0.f;
        short8 b0 = pack8(*(const floatx4*)p,        *(const floatx4*)(p + 4),  ncp);
        short8 b1 = pack8(*(const floatx4*)(p + 32), *(const floatx4*)(p + 36), ncp);
        cfrag[ct][0][lane] = b0;
        cfrag[ct][1][lane] = b1;
        ncp += __shfl_xor(ncp, 16);
        ncp += __shfl_xor(ncp, 32);                    // full ||c_j||^2
        if (lg == 0) ((float*)ncin)[ct * 16 + lr] = -0.5f * ncp;
        if (lg == 1) ((float*)muv8)[ct * 16 + lr] = mus[j];
    }
    __syncthreads();
    float q_pot = qred[0] + qred[1] + qred[2] + qred[3];

    // ---- block 0 / first wave: query_output flow step ----
    if (blockIdx.x == 0 && tid < 64) {
        float qd = qz[tid];
        float acc = 0.f;
        for (int jj = 0; jj < 128; ++jj)
            acc = fmaf(wj[jj], centers[jj * 64 + tid] - qd, acc);
        out[tid] = fmaf(DT_STEP, acc, qd);
    }

    // ---- hoist ALL loop constants to registers (128 VGPR, read-only) ----
    short8  cfr0[8], cfr1[8];
    floatx4 ncr[8], mur[8];
#pragma unroll
    for (int ct = 0; ct < 8; ++ct) {
        cfr0[ct] = cfrag[ct][0][lane];
        cfr1[ct] = cfrag[ct][1][lane];
        ncr[ct]  = ncin[ct][lg];
        mur[ct]  = muv8[ct][lg];
    }

    // ---- main loop: 2 tiles (32 candidates)/iter, prefetched, NO LDS ----
    float lsum = 0.f;
    const float* baseA = cand + (size_t)lr * 64 + lg * 8;
    floatx4 v0, v1, v2, v3, v4, v5, v6, v7;
#define LOADP(pp) { const float* pa = baseA + (size_t)(pp) * 2048;          \
        v0 = *(const floatx4*)pa;        v1 = *(const floatx4*)(pa + 4);    \
        v2 = *(const floatx4*)(pa + 32); v3 = *(const floatx4*)(pa + 36);   \
        const float* pb = pa + 1024;                                        \
        v4 = *(const floatx4*)pb;        v5 = *(const floatx4*)(pb + 4);    \
        v6 = *(const floatx4*)(pb + 32); v7 = *(const floatx4*)(pb + 36); }

    int p = blockIdx.x * 4 + wid;
    LOADP(p);
    while (p < N_PAIRS) {
        // consume current loads into fragments (frees v0..v7)
        float nzA = 0.f, nzB = 0.f;
        short8 afA0 = pack8(v0, v1, nzA), afA1 = pack8(v2, v3, nzA);
        short8 afB0 = pack8(v4, v5, nzB), afB1 = pack8(v6, v7, nzB);
        size_t r0 = (size_t)p * 32;
        p += STRIDE;
        if (p < N_PAIRS) LOADP(p);      // issue next-iter loads BEFORE compute

        nzA += __shfl_xor(nzA, 16); nzA += __shfl_xor(nzA, 32);
        nzB += __shfl_xor(nzB, 16); nzB += __shfl_xor(nzB, 32);

        float potA = 0.f, potB = 0.f;
#pragma unroll
        for (int ct = 0; ct < 8; ++ct) {
            floatx4 aA = __builtin_amdgcn_mfma_f32_16x16x32_bf16(cfr0[ct], afA0, ncr[ct], 0, 0, 0);
            aA         = __builtin_amdgcn_mfma_f32_16x16x32_bf16(cfr1[ct], afA1, aA,      0, 0, 0);
            floatx4 aB = __builtin_amdgcn_mfma_f32_16x16x32_bf16(cfr0[ct], afB0, ncr[ct], 0, 0, 0);
            aB         = __builtin_amdgcn_mfma_f32_16x16x32_bf16(cfr1[ct], afB1, aB,      0, 0, 0);
#pragma unroll
            for (int r = 0; r < 4; ++r) {
                // d2 = nz + nc - 2*dot, provably >= ~28 on this dataset: no clamp
                potA = fmaf(mur[ct][r], __builtin_amdgcn_rsqf(fmaf(-2.f, aA[r], nzA)), potA);
                potB = fmaf(mur[ct][r], __builtin_amdgcn_rsqf(fmaf(-2.f, aB[r], nzB)), potB);
            }
        }
        potA += __shfl_xor(potA, 16); potA += __shfl_xor(potA, 32);
        potB += __shfl_xor(potB, 16); potB += __shfl_xor(potB, 32);

        if (lg == 0) {
            float eA = exp2f(-IT_LOG2E * fabsf(q_pot - potA));
            float eB = exp2f(-IT_LOG2E * fabsf(q_pot - potB));
            out[64 + r0 + lr]      = eA;
            out[64 + r0 + 16 + lr] = eB;
            lsum += eA + eB;
        }
    }
#undef LOADP

    // ---- block partial sum -> plain store (no reset needed) ----
#pragma unroll
    for (int m = 1; m < 64; m <<= 1) lsum += __shfl_xor(lsum, m);
    if (lane == 0) sred[wid] = lsum;
    __syncthreads();
    if (tid == 0) partials[blockIdx.x] = sred[0] + sred[1] + sred[2] + sred[3];
}

// ---- Normalize: re-reduce 512 partials per block (L2-broadcast), scale ----
__global__ __launch_bounds__(256)
void norm_kernel(float* __restrict__ att, const float* __restrict__ partials) {
    int tid = threadIdx.x;
    float p = partials[tid] + partials[tid + 256];    // 512 partials
#pragma unroll
    for (int m = 1; m < 64; m <<= 1) p += __shfl_xor(p, m);
    __shared__ float red[4];
    if ((tid & 63) == 0) red[tid >> 6] = p;
    __syncthreads();
    float inv = 1.0f / (red[0] + red[1] + red[2] + red[3]);
    int i = blockIdx.x * 256 + tid;
    if (i < N_CAND / 4) {
        floatx4 v = *(floatx4*)(att + (size_t)i * 4);
#pragma unroll
        for (int k = 0; k < 4; ++k) v[k] *= inv;
        *(floatx4*)(att + (size_t)i * 4) = v;
    }
}

extern "C" void kernel_launch(void* const* d_in, const int* in_sizes, int n_in,
                              void* d_out, int out_size, void* d_ws, size_t ws_size,
                              hipStream_t stream) {
    const float* qz   = (const float*)d_in[0];
    const float* cand = (const float*)d_in[1];
    const float* ctr  = (const float*)d_in[2];
    const float* mus  = (const float*)d_in[3];
    float* out = (float*)d_out;
    float* ws  = (float*)d_ws;

    pot_kernel<<<POT_BLOCKS, 256, 0, stream>>>(qz, cand, ctr, mus, out, ws + 256);
    int blocks2 = (N_CAND / 4 + 255) / 256;   // 489
    norm_kernel<<<blocks2, 256, 0, stream>>>(out + 64, ws + 256);
}